// Round 1
// baseline (96.283 us; speedup 1.0000x reference)
//
#include <hip/hip_runtime.h>

#define NBODY 8192
#define BLOCK 256
#define IPT 2                       // i-bodies per thread
#define ITILE (BLOCK * IPT)         // 512 i-bodies per block
#define NITILES (NBODY / ITILE)     // 16
#define SLABS 64                    // j-slabs
#define JCHUNK (NBODY / SLABS)      // 128 j-bodies per slab
#define NF (NBODY * 3)              // 24576 output floats
#define SOFT2 1.0e-4f               // 0.01^2

// Pack (x,y,z,m) into one float4 per body so the force kernel's wave-uniform
// j-reads can be a single s_load_dwordx4 (scalar pipe + K$, no DS/VMEM cost).
__global__ __launch_bounds__(BLOCK) void pack_kernel(
    const float* __restrict__ pos, const float* __restrict__ mass,
    float4* __restrict__ pw) {
  const int i = blockIdx.x * BLOCK + threadIdx.x;
  pw[i] = make_float4(pos[i * 3 + 0], pos[i * 3 + 1], pos[i * 3 + 2], mass[i]);
}

// 2-D grid: blockIdx.x = 512-body i-tile, blockIdx.y = 128-body j-slab.
// Each thread owns 2 i-bodies (IPT=2): per j-body load we do 2 full pair
// interactions -> load traffic halved, ILP doubled vs the 1-body version.
// No LDS, no __syncthreads, no atomics: partials go to ws, reduced after.
__global__ __launch_bounds__(BLOCK) void force_kernel(
    const float4* __restrict__ pw, float* __restrict__ part) {
  const int t = threadIdx.x;
  const int i1 = blockIdx.x * ITILE + t;
  const int i2 = i1 + BLOCK;
  const int jbase = blockIdx.y * JCHUNK;

  const float4 p1 = pw[i1];
  const float4 p2 = pw[i2];
  const float x1 = p1.x, y1 = p1.y, z1 = p1.z;
  const float x2 = p2.x, y2 = p2.y, z2 = p2.z;

  float ax1 = 0.f, ay1 = 0.f, az1 = 0.f;
  float ax2 = 0.f, ay2 = 0.f, az2 = 0.f;

#pragma unroll 8
  for (int k = 0; k < JCHUNK; ++k) {
    // Wave-uniform address: compiler promotes to s_load_dwordx4. Each VALU op
    // below reads at most one SGPR operand (o.x/o.y/o.z/o.w) - legal encoding.
    const float4 o = pw[jbase + k];

    float dx1 = o.x - x1, dy1 = o.y - y1, dz1 = o.z - z1;
    float dx2 = o.x - x2, dy2 = o.y - y2, dz2 = o.z - z2;
    float r21 = fmaf(dx1, dx1, fmaf(dy1, dy1, fmaf(dz1, dz1, SOFT2)));
    float r22 = fmaf(dx2, dx2, fmaf(dy2, dy2, fmaf(dz2, dz2, SOFT2)));
    float in1 = __builtin_amdgcn_rsqf(r21);  // v_rsq_f32 (trans pipe, hidden)
    float in2 = __builtin_amdgcn_rsqf(r22);
    float w1 = o.w * (in1 * in1 * in1);      // m_j * r^-3
    float w2 = o.w * (in2 * in2 * in2);
    ax1 = fmaf(w1, dx1, ax1);
    ay1 = fmaf(w1, dy1, ay1);
    az1 = fmaf(w1, dz1, az1);
    ax2 = fmaf(w2, dx2, ax2);
    ay2 = fmaf(w2, dy2, ay2);
    az2 = fmaf(w2, dz2, az2);
  }

  // Per-slab partials: plain stores, no contention, no memset dependency.
  float* __restrict__ dst = part + (size_t)blockIdx.y * NF;
  dst[i1 * 3 + 0] = ax1;
  dst[i1 * 3 + 1] = ay1;
  dst[i1 * 3 + 2] = az1;
  dst[i2 * 3 + 0] = ax2;
  dst[i2 * 3 + 1] = ay2;
  dst[i2 * 3 + 2] = az2;
}

// Sum the 64 slab partials per output element. 6 MB read, coalesced across
// threads for each slab index; ~3 us.
__global__ __launch_bounds__(BLOCK) void reduce_kernel(
    const float* __restrict__ part, float* __restrict__ out) {
  const int idx = blockIdx.x * BLOCK + threadIdx.x;  // < NF
  float s = 0.f;
#pragma unroll
  for (int sl = 0; sl < SLABS; ++sl) s += part[(size_t)sl * NF + idx];
  out[idx] = s;
}

extern "C" void kernel_launch(void* const* d_in, const int* in_sizes, int n_in,
                              void* d_out, int out_size, void* d_ws,
                              size_t ws_size, hipStream_t stream) {
  const float* pos = (const float*)d_in[0];
  const float* mass = (const float*)d_in[1];
  float* out = (float*)d_out;

  // ws layout: [0, 128KB) packed float4 bodies; [128KB, 128KB+6MB) partials.
  float4* pw = (float4*)d_ws;
  float* part = (float*)d_ws + (size_t)NBODY * 4;

  pack_kernel<<<NBODY / BLOCK, BLOCK, 0, stream>>>(pos, mass, pw);
  force_kernel<<<dim3(NITILES, SLABS), BLOCK, 0, stream>>>(pw, part);
  reduce_kernel<<<NF / BLOCK, BLOCK, 0, stream>>>(part, out);
}

// Round 2
// 85.567 us; speedup vs baseline: 1.1252x; 1.1252x over previous
//
#include <hip/hip_runtime.h>

typedef float v2f __attribute__((ext_vector_type(2)));

#define NBODY 8192
#define BLOCK 256
#define IPT 4                       // i-bodies per thread (2 packed pairs)
#define ITILE (BLOCK * IPT)         // 1024 i-bodies per block
#define NITILES (NBODY / ITILE)     // 8
#define SLABS 128                   // j-slabs
#define JCHUNK (NBODY / SLABS)      // 64 j-bodies per slab
#define NF (NBODY * 3)              // 24576 output floats
#define SOFT2 1.0e-4f               // 0.01^2

static __device__ __forceinline__ v2f splat(float s) { return (v2f){s, s}; }

// grid (8, 128): blockIdx.x = 1024-body i-tile, blockIdx.y = 64-body j-slab.
// j-tile staged in LDS (wave-uniform ds_read_b128 broadcast, round-0 proven
// path; scalar-promotion of uniform global loads regressed in round 1 due to
// out-of-order SMEM returns forcing lgkmcnt(0) drains).
// Each thread owns 4 i-bodies packed as TWO float2 lanes -> v_pk_fma_f32 /
// v_pk_mul_f32 halve the full-rate VALU issue count (packed-FP32 is the only
// way to the 157 TF f32 peak). Per j per wave: 24 pk ops (48 cy) + 4 rsq
// (32 cy) vs 12 cy DS -> DS pipe at ~60%, VALU-issue-bound.
__global__ __launch_bounds__(BLOCK) void force_kernel(
    const float* __restrict__ pos, const float* __restrict__ mass,
    float* __restrict__ part) {
  __shared__ float4 tile[JCHUNK];

  const int t = threadIdx.x;
  const int j0 = blockIdx.y * JCHUNK;
  if (t < JCHUNK) {
    const int j = j0 + t;
    tile[t] =
        make_float4(pos[j * 3 + 0], pos[j * 3 + 1], pos[j * 3 + 2], mass[j]);
  }

  const int ib = blockIdx.x * ITILE + t;  // i-bodies: ib + {0,1,2,3}*BLOCK
  float xs[4], ys[4], zs[4];
#pragma unroll
  for (int p = 0; p < 4; ++p) {
    const int i = ib + p * BLOCK;
    xs[p] = pos[i * 3 + 0];
    ys[p] = pos[i * 3 + 1];
    zs[p] = pos[i * 3 + 2];
  }
  const v2f xA = {xs[0], xs[1]}, xB = {xs[2], xs[3]};
  const v2f yA = {ys[0], ys[1]}, yB = {ys[2], ys[3]};
  const v2f zA = {zs[0], zs[1]}, zB = {zs[2], zs[3]};

  v2f axA = {0.f, 0.f}, ayA = {0.f, 0.f}, azA = {0.f, 0.f};
  v2f axB = {0.f, 0.f}, ayB = {0.f, 0.f}, azB = {0.f, 0.f};

  __syncthreads();

#pragma unroll 4
  for (int k = 0; k < JCHUNK; ++k) {
    const float4 o = tile[k];  // wave-uniform -> ds_read_b128 broadcast
    const v2f ox = splat(o.x), oy = splat(o.y), oz = splat(o.z);
    const v2f om = splat(o.w);

    v2f dxA = ox - xA, dyA = oy - yA, dzA = oz - zA;
    v2f dxB = ox - xB, dyB = oy - yB, dzB = oz - zB;
    // -ffp-contract=fast (HIP default) -> 3 v_pk_fma_f32 each
    v2f r2A = dxA * dxA + (dyA * dyA + (dzA * dzA + splat(SOFT2)));
    v2f r2B = dxB * dxB + (dyB * dyB + (dzB * dzB + splat(SOFT2)));

    const float iA0 = __builtin_amdgcn_rsqf(r2A.x);  // v_rsq_f32 (trans)
    const float iA1 = __builtin_amdgcn_rsqf(r2A.y);
    const float iB0 = __builtin_amdgcn_rsqf(r2B.x);
    const float iB1 = __builtin_amdgcn_rsqf(r2B.y);
    const v2f iA = {iA0, iA1}, iB = {iB0, iB1};

    v2f wA = ((iA * iA) * iA) * om;  // m_j * r^-3, 3 pk_mul
    v2f wB = ((iB * iB) * iB) * om;

    axA += wA * dxA;
    ayA += wA * dyA;
    azA += wA * dzA;
    axB += wB * dxB;
    ayB += wB * dyB;
    azB += wB * dzB;
  }

  // SoA partials [slab][comp][body]: per-wave stores are 4B-stride coalesced.
  float* __restrict__ dst = part + (size_t)blockIdx.y * NF;
  const float ax[4] = {axA.x, axA.y, axB.x, axB.y};
  const float ay[4] = {ayA.x, ayA.y, ayB.x, ayB.y};
  const float az[4] = {azA.x, azA.y, azB.x, azB.y};
#pragma unroll
  for (int p = 0; p < 4; ++p) {
    const int i = ib + p * BLOCK;
    dst[0 * NBODY + i] = ax[p];
    dst[1 * NBODY + i] = ay[p];
    dst[2 * NBODY + i] = az[p];
  }
}

// Sum 128 slab partials per output element: 12.6 MB coalesced reads, ~2-3 us.
__global__ __launch_bounds__(BLOCK) void reduce_kernel(
    const float* __restrict__ part, float* __restrict__ out) {
  const int idx = blockIdx.x * BLOCK + threadIdx.x;  // < NF, SoA index
  const int c = idx >> 13;          // component (idx / NBODY)
  const int b = idx & (NBODY - 1);  // body
  float s0 = 0.f, s1 = 0.f, s2 = 0.f, s3 = 0.f;
#pragma unroll 8
  for (int sl = 0; sl < SLABS; sl += 4) {
    s0 += part[(size_t)(sl + 0) * NF + idx];
    s1 += part[(size_t)(sl + 1) * NF + idx];
    s2 += part[(size_t)(sl + 2) * NF + idx];
    s3 += part[(size_t)(sl + 3) * NF + idx];
  }
  out[b * 3 + c] = (s0 + s1) + (s2 + s3);
}

extern "C" void kernel_launch(void* const* d_in, const int* in_sizes, int n_in,
                              void* d_out, int out_size, void* d_ws,
                              size_t ws_size, hipStream_t stream) {
  const float* pos = (const float*)d_in[0];
  const float* mass = (const float*)d_in[1];
  float* out = (float*)d_out;
  float* part = (float*)d_ws;  // 128 * 24576 * 4 B = 12.6 MB

  force_kernel<<<dim3(NITILES, SLABS), BLOCK, 0, stream>>>(pos, mass, part);
  reduce_kernel<<<NF / BLOCK, BLOCK, 0, stream>>>(part, out);
}